// Round 9
// baseline (4338.466 us; speedup 1.0000x reference)
//
#include <hip/hip_runtime.h>

// ---------------------------------------------------------------------------
// SparseConvUNet forward, round 9: single persistent mega-kernel.
// 256 blocks x 1024 threads (co-resident), software grid barrier between
// phases. Convs gather RAW f32 of the previous layer and normalize-on-gather
// (BN stats finalized per phase from 8-replica f64 atomics); weights in
// registers per wave (8-way tap split across 16 waves); LDS k-split reduce.
// ---------------------------------------------------------------------------

typedef short bf16x8 __attribute__((ext_vector_type(8)));
typedef float f32x4 __attribute__((ext_vector_type(4)));
typedef unsigned short ushort_t;

constexpr int D1 = 48, DIM2 = 24, DIM3 = 12;
constexpr int N1 = D1 * D1 * D1;        // 110592
constexpr int N2 = DIM2 * DIM2 * DIM2;  // 13824
constexpr int N3 = DIM3 * DIM3 * DIM3;  // 1728
constexpr int NBLK = 256, NTHR = 1024;
constexpr int GSZ = NBLK * NTHR;

// ---- workspace layout (float offsets) ----
constexpr size_t OFF_A    = 0;          // x0 raw (N1*32)
constexpr size_t OFF_R1   = 3538944;    // b1a raw; later h1 raw (N1*32)
constexpr size_t OFF_CAT1 = 7077888;    // x1 | u1 raw (N1*64)
constexpr size_t OFF_IDB1 = 14155776;   // sc1 out (N1*32)
constexpr size_t OFF_T1R  = 17694720;   // t1 raw (N1*32)
constexpr size_t OFF_D1R  = 21233664;   // d1 raw; later idb2 (N2*64)
constexpr size_t OFF_R3   = 22118400;   // b2a raw; later h2 raw (N2*64)
constexpr size_t OFF_CAT2 = 23003136;   // x2 | u2 raw (N2*128)
constexpr size_t OFF_T2R  = 24772608;   // t2 raw (N2*64)
constexpr size_t OFF_D2R  = 25657344;   // d2 raw (N3*96)
constexpr size_t OFF_R4   = 25823232;   // b3a raw (N3*96)
constexpr size_t OFF_X3R  = 25989120;   // x3 raw (N3*96)
constexpr size_t OFF_WT   = 26155008;   // bf16 weights (1,347,584 us = 673,792 fl)
constexpr size_t OFF_STATS= 26828800;   // 16 slots * (8 reps * 256 doubles) = 65,536 fl
constexpr size_t OFF_BAR  = 26894336;   // bar[0..1] + cnt[4..6]  (16 ints)
constexpr size_t OFF_L1   = 26894352;
constexpr size_t OFF_L2   = 27004944;
constexpr size_t OFF_L3   = 27018768;
constexpr size_t OFF_M1   = 27020496;   // uchar, in float units
constexpr size_t OFF_M2   = 27048144;
constexpr size_t OFF_M3   = 27051600;

// bf16 weight starts (ushort units), layout [k][co][cipad]
// jobs: 0 w_in, 1 b1a, 2 b1b, 3 d1, 4 b2a, 5 b2b, 6 d2, 7 b3a, 8 b3b,
//       9 t2a(128ci), 10 t2b, 11 t1a, 12 t1b, 13 u2, 14 u1
constexpr int WTS[16] = {0, 27648, 55296, 82944, 99328, 209920, 320512,
                         369664, 618496, 867328, 1088512, 1199104, 1254400,
                         1282048, 1331200, 1347584};
constexpr int WTOT = 1347584;

__device__ inline ushort_t f2bf(float f) {
  union { float f; unsigned u; } x; x.f = f;
  unsigned u = x.u + 0x7FFF + ((x.u >> 16) & 1);
  return (ushort_t)(u >> 16);
}

struct P {
  const float* x;
  const float* wsrc[15];
  const float* wsc2;
  const float* wsc1;
  float* out;
  float* W;
  int wts[16];
  short cirt[15], cip[15], cot[15];
};

// ---- software grid barrier (all NBLK blocks resident) ----
__device__ __forceinline__ void gridbar(int* bar) {
  __threadfence();
  __syncthreads();
  if (threadIdx.x == 0) {
    int g = __hip_atomic_load(bar + 1, __ATOMIC_ACQUIRE, __HIP_MEMORY_SCOPE_AGENT);
    int a = __hip_atomic_fetch_add(bar, 1, __ATOMIC_ACQ_REL, __HIP_MEMORY_SCOPE_AGENT);
    if (a == NBLK - 1) {
      __hip_atomic_store(bar, 0, __ATOMIC_RELAXED, __HIP_MEMORY_SCOPE_AGENT);
      __hip_atomic_fetch_add(bar + 1, 1, __ATOMIC_ACQ_REL, __HIP_MEMORY_SCOPE_AGENT);
    } else {
      while (__hip_atomic_load(bar + 1, __ATOMIC_ACQUIRE, __HIP_MEMORY_SCOPE_AGENT) == g)
        __builtin_amdgcn_s_sleep(2);
    }
  }
  __syncthreads();
}

// ---------------------------------------------------------------------------
// conv phase: gather raw f32 + normalize-on-gather + MFMA, weights in regs.
// 16 waves = 2 voxel-groups x 8 tap-splits; tile = 32 voxels; CB co/block.
// ---------------------------------------------------------------------------
template <int CIPAD, int CB, int KK, bool UP, int DD, bool NORM, int CIRAW>
__device__ void conv_phase(
    float* shm,
    const float* __restrict__ in, int istr, int nIn,
    const ushort_t* __restrict__ wt, int COUT,
    const unsigned char* __restrict__ msk,
    const double* __restrict__ stA, const double* __restrict__ stB, int csplit,
    float* __restrict__ out, int ostr, int ooff,
    const float* __restrict__ res, int rstr,
    double* __restrict__ stOut,
    const int* __restrict__ list, int n) {
  constexpr int KCH = CIPAD / 32;
  constexpr int NCO = CB / 16;
  constexpr int TPS = (KK + 7) / 8;
  constexpr int ETOT = 2 * NCO * 256;
  float* red  = shm;               // [8][2][NCO*4][64]
  float* s_iv = shm + 8192;        // [CIPAD]
  float* s_mv = shm + 8320;        // [CIPAD]
  float* sred = shm + 8448;        // [2*CB]

  const int t = threadIdx.x;
  const int wv = t >> 6, ln = t & 63;
  const int vg = wv & 1, ks = wv >> 1;
  const int fr = ln & 15, kg = ln >> 4;
  const int ncob = COUT / CB;
  const int g2 = NBLK / ncob;
  const int cob = (int)blockIdx.x / g2;
  const bool act = (cob < ncob);
  const int cobe = act ? cob : 0;
  const int coblk = cobe * CB;
  const int ntiles = (n + 31) >> 5;
  const int tstart = act ? ((int)blockIdx.x - cob * g2) : ntiles;

  if (NORM && t < CIPAD) {
    const double* s = (t < csplit) ? (stA + t) : (stB + (t - csplit));
    double sm = 0.0, sq = 0.0;
#pragma unroll
    for (int r = 0; r < 8; r++) { sm += s[r * 256]; sq += s[r * 256 + 128]; }
    double mu = sm / nIn, var = sq / nIn - mu * mu;
    float iv = rsqrtf((float)fmax(var, 0.0) + 1e-4f);
    s_iv[t] = iv;
    s_mv[t] = (float)mu * iv;
  }
  if (t < 2 * CB) sred[t] = 0.f;
  __syncthreads();

  float ivv[KCH][8], mvv[KCH][8];
  if (NORM) {
#pragma unroll
    for (int c = 0; c < KCH; c++)
#pragma unroll
      for (int q = 0; q < 8; q++) {
        int ch = c * 32 + kg * 8 + q;
        ivv[c][q] = s_iv[ch];
        mvv[c][q] = s_mv[ch];
      }
  }

  bf16x8 wr[TPS][KCH][NCO];
#pragma unroll
  for (int j = 0; j < TPS; j++) {
    int k = ks + j * 8;
    int kc = (k < KK) ? k : KK - 1;
#pragma unroll
    for (int c = 0; c < KCH; c++)
#pragma unroll
      for (int f = 0; f < NCO; f++)
        wr[j][c][f] = *(const bf16x8*)(wt +
            ((size_t)kc * COUT + coblk + f * 16 + fr) * CIPAD + c * 32 + kg * 8);
  }

  float smr = 0.f, sqr = 0.f;

  for (int tile = tstart; tile < ntiles; tile += g2) {
    int base = tile * 32;
    int i = base + vg * 16 + fr;
    int av = (i < n) ? list[i] : -1;
    int vv = av < 0 ? 0 : av;
    int ad = vv / (DD * DD), ah = (vv / DD) % DD, aw = vv % DD;
    int pidx = 0, corner = -1;
    if (UP) {
      constexpr int DC = DD / 2;
      pidx = (((ad >> 1) * DC) + (ah >> 1)) * DC + (aw >> 1);
      corner = ((ad & 1) << 2) | ((ah & 1) << 1) | (aw & 1);
    }
    constexpr int GDI = UP ? (DD / 2) : ((KK == 8) ? 2 * DD : DD);

    float aF[2][KCH][8];
    float okf[2];

    auto LOADT = [&](int st, int j) {
      int k = ks + j * 8;
      bool ok;
      int nix;
      if (UP) {
        ok = (av >= 0) && (corner == k);
        nix = ok ? pidx : 0;
      } else if (KK == 27) {
        int kd = k / 9 - 1, kh = (k / 3) % 3 - 1, kw = k % 3 - 1;
        int nd = ad + kd, nh = ah + kh, nw = aw + kw;
        ok = (k < KK) && (av >= 0) && ((unsigned)nd < (unsigned)DD) &&
             ((unsigned)nh < (unsigned)DD) && ((unsigned)nw < (unsigned)DD);
        nix = ok ? (nd * DD + nh) * DD + nw : 0;
      } else {
        int kd = (k >> 2) & 1, kh = (k >> 1) & 1, kw = k & 1;
        ok = (av >= 0);
        nix = ok ? ((2 * ad + kd) * GDI + (2 * ah + kh)) * GDI + (2 * aw + kw) : 0;
      }
      if (NORM) { if (msk) ok = ok && (msk[nix] != 0); }
      okf[st] = ok ? 1.f : 0.f;
      if (CIRAW == 6) {
        if (kg == 0) {
          const float* ap = in + (size_t)nix * 6;
          float2 l0 = *(const float2*)ap;
          float2 l1 = *(const float2*)(ap + 2);
          float2 l2 = *(const float2*)(ap + 4);
          aF[st][0][0] = l0.x; aF[st][0][1] = l0.y;
          aF[st][0][2] = l1.x; aF[st][0][3] = l1.y;
          aF[st][0][4] = l2.x; aF[st][0][5] = l2.y;
          aF[st][0][6] = 0.f;  aF[st][0][7] = 0.f;
        } else {
#pragma unroll
          for (int q = 0; q < 8; q++) aF[st][0][q] = 0.f;
        }
      } else {
#pragma unroll
        for (int c = 0; c < KCH; c++) {
          const float* ap = in + (size_t)nix * istr + c * 32 + kg * 8;
          float4 u0 = *(const float4*)ap;
          float4 u1 = *(const float4*)(ap + 4);
          aF[st][c][0] = u0.x; aF[st][c][1] = u0.y; aF[st][c][2] = u0.z; aF[st][c][3] = u0.w;
          aF[st][c][4] = u1.x; aF[st][c][5] = u1.y; aF[st][c][6] = u1.z; aF[st][c][7] = u1.w;
        }
      }
    };

    f32x4 acc[NCO];
#pragma unroll
    for (int f = 0; f < NCO; f++) acc[f] = (f32x4){0.f, 0.f, 0.f, 0.f};

    LOADT(0, 0);
#pragma unroll
    for (int j = 0; j < TPS; j++) {
      if (j + 1 < TPS) LOADT((j + 1) & 1, j + 1);
      const int st = j & 1;
#pragma unroll
      for (int c = 0; c < KCH; c++) {
        bf16x8 afr;
#pragma unroll
        for (int q = 0; q < 8; q++) {
          float y;
          if (NORM) y = fmaxf(fmaf(aF[st][c][q], ivv[c][q], -mvv[c][q]), 0.f) * okf[st];
          else      y = aF[st][c][q] * okf[st];
          afr[q] = (short)f2bf(y);
        }
#pragma unroll
        for (int f = 0; f < NCO; f++)
          acc[f] = __builtin_amdgcn_mfma_f32_16x16x32_bf16(afr, wr[j][c][f], acc[f], 0, 0, 0);
      }
    }

#pragma unroll
    for (int f = 0; f < NCO; f++)
#pragma unroll
      for (int r = 0; r < 4; r++)
        red[(((ks * 2 + vg) * (NCO * 4)) + (f * 4 + r)) * 64 + ln] = acc[f][r];
    __syncthreads();
    if (t < ETOT) {
      int ln2 = t & 63, r = (t >> 6) & 3, f = (t >> 8) % NCO, vg2 = t / (256 * NCO);
      float sv = 0.f;
#pragma unroll
      for (int q = 0; q < 8; q++)
        sv += red[(((q * 2 + vg2) * (NCO * 4)) + (f * 4 + r)) * 64 + ln2];
      int slot = vg2 * 16 + (ln2 >> 4) * 4 + r;
      int ii = base + slot;
      int v = (ii < n) ? list[ii] : -1;
      if (v >= 0) {
        int gco = coblk + f * 16 + (ln2 & 15);
        float val = sv;
        if (res) val += res[(size_t)v * rstr + gco];
        out[(size_t)v * ostr + ooff + gco] = val;
        smr += val;
        sqr += val * val;
      }
    }
    __syncthreads();
  }

  if (t < ETOT && (smr != 0.f || sqr != 0.f)) {
    int ln2 = t & 63, f = (t >> 8) % NCO;
    atomicAdd(&sred[f * 16 + (ln2 & 15)], smr);
    atomicAdd(&sred[CB + f * 16 + (ln2 & 15)], sqr);
  }
  __syncthreads();
  if (t < CB && act) {
    double* sr = stOut + (size_t)((int)blockIdx.x & 7) * 256;
    atomicAdd(&sr[coblk + t], (double)sred[t]);
    atomicAdd(&sr[128 + coblk + t], (double)sred[CB + t]);
  }
}

// ---------------------------------------------------------------------------
// the mega-kernel
// ---------------------------------------------------------------------------
__global__ __launch_bounds__(NTHR, 8) void k_unet(P p) {
  __shared__ float shm[8704];
  float* W = p.W;
  double* SB = (double*)(W + OFF_STATS);
  int* BAR = (int*)(W + OFF_BAR);
  int* CNT = BAR + 4;
  int* L1 = (int*)(W + OFF_L1);
  int* L2 = (int*)(W + OFF_L2);
  int* L3 = (int*)(W + OFF_L3);
  unsigned char* M1 = (unsigned char*)(W + OFF_M1);
  unsigned char* M2 = (unsigned char*)(W + OFF_M2);
  unsigned char* M3 = (unsigned char*)(W + OFF_M3);
  ushort_t* WT = (ushort_t*)(W + OFF_WT);
  float* A    = W + OFF_A;
  float* R1   = W + OFF_R1;
  float* CAT1 = W + OFF_CAT1;
  float* IDB1 = W + OFF_IDB1;
  float* T1R  = W + OFF_T1R;
  float* D1R  = W + OFF_D1R;
  float* R3   = W + OFF_R3;
  float* CAT2 = W + OFF_CAT2;
  float* T2R  = W + OFF_T2R;
  float* D2R  = W + OFF_D2R;
  float* R4   = W + OFF_R4;
  float* X3R  = W + OFF_X3R;

  const int t = threadIdx.x;
  const int gid = (int)blockIdx.x * NTHR + t;

  auto S = [&](int i) { return SB + (size_t)i * 2048; };
  // slots: 0 x0, 1 b1a, 2 x1, 3 d1, 4 b2a, 5 x2, 6 d2, 7 b3a, 8 x3,
  //        9 u2, 10 h2, 11 t2, 12 u1, 13 h1, 14 t1

  // ---- S0: zero stats ----
  for (int i = gid; i < 16 * 2048; i += GSZ) SB[i] = 0.0;
  gridbar(BAR);

  // ---- S1: mask1 + weight prep ----
  for (int v = gid; v < N1; v += GSZ) {
    const float* px = p.x + (size_t)v * 6;
    bool a = px[0] != 0.f || px[1] != 0.f || px[2] != 0.f ||
             px[3] != 0.f || px[4] != 0.f || px[5] != 0.f;
    M1[v] = a ? 1 : 0;
    if (a) L1[atomicAdd(&CNT[0], 1)] = v;
  }
  for (int e = gid; e < WTOT; e += GSZ) {
    int j = 0;
#pragma unroll
    for (int jj = 0; jj < 15; jj++)
      if (e >= p.wts[jj + 1]) j = jj + 1;
    int le = e - p.wts[j];
    int CIP = p.cip[j], CO = p.cot[j], CIRT = p.cirt[j];
    int ci = le % CIP;
    int co = (le / CIP) % CO;
    int k = le / (CIP * CO);
    float v = (ci < CIRT) ? p.wsrc[j][((size_t)k * CIRT + ci) * CO + co] : 0.f;
    WT[e] = f2bf(v);
  }
  gridbar(BAR);

  // ---- S2: pool masks + lists ----
  for (int v = gid; v < N2; v += GSZ) {
    int w = v % DIM2, h = (v / DIM2) % DIM2, d = v / (DIM2 * DIM2);
    bool a = false;
    for (int i2 = 0; i2 < 2; i2++)
      for (int j2 = 0; j2 < 2; j2++)
        for (int k2 = 0; k2 < 2; k2++)
          a |= (M1[((2 * d + i2) * D1 + (2 * h + j2)) * D1 + (2 * w + k2)] != 0);
    M2[v] = a ? 1 : 0;
    if (a) L2[atomicAdd(&CNT[1], 1)] = v;
  }
  for (int v = gid; v < N3; v += GSZ) {
    int w = v % DIM3, h = (v / DIM3) % DIM3, d = v / (DIM3 * DIM3);
    bool a = false;
    for (int i2 = 0; i2 < 4 && !a; i2++)
      for (int j2 = 0; j2 < 4 && !a; j2++)
        for (int k2 = 0; k2 < 4; k2++)
          if (M1[((4 * d + i2) * D1 + (4 * h + j2)) * D1 + (4 * w + k2)] != 0) { a = true; break; }
    M3[v] = a ? 1 : 0;
    if (a) L3[atomicAdd(&CNT[2], 1)] = v;
  }
  gridbar(BAR);

  const int n1 = __hip_atomic_load(&CNT[0], __ATOMIC_RELAXED, __HIP_MEMORY_SCOPE_AGENT);
  const int n2 = __hip_atomic_load(&CNT[1], __ATOMIC_RELAXED, __HIP_MEMORY_SCOPE_AGENT);
  const int n3 = __hip_atomic_load(&CNT[2], __ATOMIC_RELAXED, __HIP_MEMORY_SCOPE_AGENT);

  // ---- level 1 down ----
  conv_phase<32, 32, 27, false, D1, false, 6>(shm, p.x, 6, n1, WT + WTS[0], 32,
      nullptr, nullptr, nullptr, 32, A, 32, 0, nullptr, 0, S(0), L1, n1);          // x0
  gridbar(BAR);
  conv_phase<32, 32, 27, false, D1, true, 0>(shm, A, 32, n1, WT + WTS[1], 32,
      M1, S(0), S(0), 32, R1, 32, 0, nullptr, 0, S(1), L1, n1);                    // b1a
  gridbar(BAR);
  conv_phase<32, 32, 27, false, D1, true, 0>(shm, R1, 32, n1, WT + WTS[2], 32,
      M1, S(1), S(1), 32, CAT1, 64, 0, A, 32, S(2), L1, n1);                       // x1
  gridbar(BAR);
  conv_phase<32, 32, 8, false, DIM2, true, 0>(shm, CAT1, 64, n1, WT + WTS[3], 64,
      M1, S(2), S(2), 32, D1R, 64, 0, nullptr, 0, S(3), L2, n2);                   // d1
  gridbar(BAR);

  // ---- level 2 ----
  conv_phase<64, 32, 27, false, DIM2, true, 0>(shm, D1R, 64, n2, WT + WTS[4], 64,
      M2, S(3), S(3), 64, R3, 64, 0, nullptr, 0, S(4), L2, n2);                    // b2a
  gridbar(BAR);
  conv_phase<64, 32, 27, false, DIM2, true, 0>(shm, R3, 64, n2, WT + WTS[5], 64,
      M2, S(4), S(4), 64, CAT2, 128, 0, D1R, 64, S(5), L2, n2);                    // x2
  gridbar(BAR);
  conv_phase<64, 32, 8, false, DIM3, true, 0>(shm, CAT2, 128, n2, WT + WTS[6], 96,
      M2, S(5), S(5), 64, D2R, 96, 0, nullptr, 0, S(6), L3, n3);                   // d2
  gridbar(BAR);

  // ---- level 3 ----
  conv_phase<96, 32, 27, false, DIM3, true, 0>(shm, D2R, 96, n3, WT + WTS[7], 96,
      M3, S(6), S(6), 96, R4, 96, 0, nullptr, 0, S(7), L3, n3);                    // b3a
  gridbar(BAR);
  conv_phase<96, 32, 27, false, DIM3, true, 0>(shm, R4, 96, n3, WT + WTS[8], 96,
      M3, S(7), S(7), 96, X3R, 96, 0, D2R, 96, S(8), L3, n3);                      // x3
  gridbar(BAR);
  conv_phase<96, 32, 8, true, DIM2, true, 0>(shm, X3R, 96, n3, WT + WTS[13], 64,
      nullptr, S(8), S(8), 96, CAT2, 128, 64, nullptr, 0, S(9), L2, n2);           // u2
  gridbar(BAR);

  // ---- tail level 2: h2 (128ci) + sc2 in one phase ----
  conv_phase<128, 16, 27, false, DIM2, true, 0>(shm, CAT2, 128, n2, WT + WTS[9], 64,
      M2, S(5), S(9), 64, R3, 64, 0, nullptr, 0, S(10), L2, n2);                   // h2
  for (long e = gid; e < (long)n2 * 64; e += GSZ) {
    int i = (int)(e >> 6), o = (int)(e & 63);
    int v = L2[i];
    const float4* xr = (const float4*)(CAT2 + (size_t)v * 128);
    const float4* wq = (const float4*)(p.wsc2 + (size_t)o * 128);
    float a = 0.f;
#pragma unroll 8
    for (int c = 0; c < 32; c++) {
      float4 xv = xr[c], wv_ = wq[c];
      a += xv.x * wv_.x + xv.y * wv_.y + xv.z * wv_.z + xv.w * wv_.w;
    }
    D1R[(size_t)v * 64 + o] = a;                                                   // idb2
  }
  gridbar(BAR);
  conv_phase<64, 32, 27, false, DIM2, true, 0>(shm, R3, 64, n2, WT + WTS[10], 64,
      M2, S(10), S(10), 64, T2R, 64, 0, D1R, 64, S(11), L2, n2);                   // t2
  gridbar(BAR);
  conv_phase<64, 32, 8, true, D1, true, 0>(shm, T2R, 64, n2, WT + WTS[14], 32,
      nullptr, S(11), S(11), 64, CAT1, 64, 32, nullptr, 0, S(12), L1, n1);         // u1
  gridbar(BAR);

  // ---- tail level 1: h1 + sc1 in one phase ----
  conv_phase<64, 32, 27, false, D1, true, 0>(shm, CAT1, 64, n1, WT + WTS[11], 32,
      M1, S(2), S(12), 32, R1, 32, 0, nullptr, 0, S(13), L1, n1);                  // h1
  for (long e = gid; e < (long)n1 * 32; e += GSZ) {
    int i = (int)(e >> 5), o = (int)(e & 31);
    int v = L1[i];
    const float4* xr = (const float4*)(CAT1 + (size_t)v * 64);
    const float4* wq = (const float4*)(p.wsc1 + (size_t)o * 64);
    float a = 0.f;
#pragma unroll 8
    for (int c = 0; c < 16; c++) {
      float4 xv = xr[c], wv_ = wq[c];
      a += xv.x * wv_.x + xv.y * wv_.y + xv.z * wv_.z + xv.w * wv_.w;
    }
    IDB1[(size_t)v * 32 + o] = a;                                                  // idb1
  }
  gridbar(BAR);
  conv_phase<32, 32, 27, false, D1, true, 0>(shm, R1, 32, n1, WT + WTS[12], 32,
      M1, S(13), S(13), 32, T1R, 32, 0, IDB1, 32, S(14), L1, n1);                  // t1
  gridbar(BAR);

  // ---- final bn_relu -> dense d_out ----
  {
    if (t < 32) {
      const double* s = S(14) + t;
      double sm = 0.0, sq = 0.0;
#pragma unroll
      for (int r = 0; r < 8; r++) { sm += s[r * 256]; sq += s[r * 256 + 128]; }
      double mu = sm / n1, var = sq / n1 - mu * mu;
      float iv = rsqrtf((float)fmax(var, 0.0) + 1e-4f);
      shm[t] = iv;
      shm[32 + t] = (float)mu * iv;
    }
    __syncthreads();
    for (int g = gid; g < N1 * 8; g += GSZ) {
      int v = g >> 3, c = (g & 7) * 4;
      float4 o = make_float4(0.f, 0.f, 0.f, 0.f);
      if (M1[v]) {
        float4 xv = *(const float4*)&T1R[(size_t)v * 32 + c];
        o.x = fmaxf(fmaf(xv.x, shm[c + 0], -shm[32 + c + 0]), 0.f);
        o.y = fmaxf(fmaf(xv.y, shm[c + 1], -shm[32 + c + 1]), 0.f);
        o.z = fmaxf(fmaf(xv.z, shm[c + 2], -shm[32 + c + 2]), 0.f);
        o.w = fmaxf(fmaf(xv.w, shm[c + 3], -shm[32 + c + 3]), 0.f);
      }
      *(float4*)&p.out[(size_t)v * 32 + c] = o;
    }
  }
}

// ---------------------------------------------------------------------------
// host launch
// ---------------------------------------------------------------------------
extern "C" void kernel_launch(void* const* d_in, const int* in_sizes, int n_in,
                              void* d_out, int out_size, void* d_ws, size_t ws_size,
                              hipStream_t stream) {
  float* W = (float*)d_ws;
  // reset barrier + counters each call (deterministic)
  hipMemsetAsync(W + OFF_BAR, 0, 16 * sizeof(int), stream);

  P p;
  p.x = (const float*)d_in[0];
  const int srcIdx[15]  = {2, 3, 4, 5, 6, 7, 8, 9, 10, 13, 14, 17, 18, 11, 15};
  const short cirt[15]  = {6, 32, 32, 32, 64, 64, 64, 96, 96, 128, 64, 64, 32, 96, 64};
  const short cip[15]   = {32, 32, 32, 32, 64, 64, 64, 96, 96, 128, 64, 64, 32, 96, 64};
  const short cot[15]   = {32, 32, 32, 64, 64, 64, 96, 96, 96, 64, 64, 32, 32, 64, 32};
  for (int j = 0; j < 15; j++) {
    p.wsrc[j] = (const float*)d_in[srcIdx[j]];
    p.cirt[j] = cirt[j]; p.cip[j] = cip[j]; p.cot[j] = cot[j];
    p.wts[j] = WTS[j];
  }
  p.wts[15] = WTS[15];
  p.wsc2 = (const float*)d_in[12];
  p.wsc1 = (const float*)d_in[16];
  p.out = (float*)d_out;
  p.W = W;

  k_unet<<<dim3(NBLK), dim3(NTHR), 0, stream>>>(p);
}

// Round 10
// 551.670 us; speedup vs baseline: 7.8642x; 7.8642x over previous
//
#include <hip/hip_runtime.h>

// ---------------------------------------------------------------------------
// SparseConvUNet forward, round 10: multi-kernel (R7 structure) with BN-apply
// fused into convs (normalize-on-gather from raw f32), shortcuts fused into
// conv epilogues, weight-prep fused into mask kernel. 22 dispatches total.
// Conv: persistent blocks, weights staged in LDS (conflict-free layout),
// 8 waves = 2 voxel-groups x 4 tap-splits, register BN-stats accumulation.
// ---------------------------------------------------------------------------

typedef short bf16x8 __attribute__((ext_vector_type(8)));
typedef float f32x4 __attribute__((ext_vector_type(4)));
typedef unsigned short ushort_t;

constexpr int D1 = 48, DIM2 = 24, DIM3 = 12;
constexpr int N1 = D1 * D1 * D1;        // 110592
constexpr int N2 = DIM2 * DIM2 * DIM2;  // 13824
constexpr int N3 = DIM3 * DIM3 * DIM3;  // 1728

// ---- workspace layout (float offsets), all raw f32 activations ----
constexpr size_t OFF_A    = 0;          // x0 (N1*32)
constexpr size_t OFF_R1   = 3538944;    // b1a; later h1 (N1*32)
constexpr size_t OFF_CAT1 = 7077888;    // x1 | u1 (N1*64)
constexpr size_t OFF_T1R  = 14155776;   // t1 (N1*32)
constexpr size_t OFF_D1R  = 17694720;   // d1 (N2*64)
constexpr size_t OFF_R3   = 18579456;   // b2a; h2 (N2*64)
constexpr size_t OFF_CAT2 = 19464192;   // x2 | u2 (N2*128)
constexpr size_t OFF_T2R  = 21233664;   // t2 (N2*64)
constexpr size_t OFF_D2R  = 22118400;   // d2 (N3*96)
constexpr size_t OFF_R4   = 22284288;   // b3a (N3*96)
constexpr size_t OFF_X3R  = 22450176;   // x3 (N3*96)
constexpr size_t OFF_WT   = 22616064;   // bf16 weights (1,347,584 us)
constexpr size_t OFF_STATS= 23289856;   // 16 slots * 8 reps * 256 doubles
constexpr size_t STATS_FLOATS = 16 * 4096;
constexpr size_t OFF_CNT  = OFF_STATS + STATS_FLOATS;
constexpr size_t OFF_L1   = OFF_CNT + 16;
constexpr size_t OFF_L2   = OFF_L1 + N1;
constexpr size_t OFF_L3   = OFF_L2 + N2;
constexpr size_t OFF_M1   = OFF_L3 + N3;
constexpr size_t OFF_M2   = OFF_M1 + N1 / 4;
constexpr size_t OFF_M3   = OFF_M2 + N2 / 4;

// bf16 weight starts (ushort units), layout [k][co][cipad]
// jobs: 0 w_in, 1 b1a, 2 b1b, 3 d1, 4 b2a, 5 b2b, 6 d2, 7 b3a, 8 b3b,
//       9 t2aA(ci0:64), 10 t2aB(ci64:128), 11 t2b, 12 t1a, 13 t1b, 14 u2, 15 u1
constexpr int WTS[17] = {0, 27648, 55296, 82944, 99328, 209920, 320512,
                         369664, 618496, 867328, 977920, 1088512, 1199104,
                         1254400, 1282048, 1331200, 1347584};
constexpr int WTOT = 1347584;

__device__ inline ushort_t f2bf(float f) {
  union { float f; unsigned u; } x; x.f = f;
  unsigned u = x.u + 0x7FFF + ((x.u >> 16) & 1);
  return (ushort_t)(u >> 16);
}

// ---------------------------------------------------------------------------
// prep: mask1 + active list1 + weight conversion (fused)
// ---------------------------------------------------------------------------
struct WJobs {
  const float* src[16];
  int start[17];
  short cirtot[16], cio[16], cipad[16], cout[16];
};

__global__ __launch_bounds__(256) void k_prep(WJobs jb, const float* __restrict__ x,
                                              unsigned char* __restrict__ m,
                                              int* __restrict__ list, int* __restrict__ cnt,
                                              ushort_t* __restrict__ wt) {
  int gid = blockIdx.x * 256 + threadIdx.x;
  int gs = gridDim.x * 256;
  for (int v = gid; v < N1; v += gs) {
    const float* p = x + (size_t)v * 6;
    bool a = (p[0] != 0.f) || (p[1] != 0.f) || (p[2] != 0.f) ||
             (p[3] != 0.f) || (p[4] != 0.f) || (p[5] != 0.f);
    m[v] = a ? 1 : 0;
    if (a) { int pos = atomicAdd(cnt, 1); list[pos] = v; }
  }
  for (int e = gid; e < WTOT; e += gs) {
    int j = 0;
#pragma unroll
    for (int jj = 0; jj < 16; jj++)
      if (e >= jb.start[jj + 1]) j = jj + 1;
    int le = e - jb.start[j];
    int CIP = jb.cipad[j], CO = jb.cout[j], CIRT = jb.cirtot[j], CIO = jb.cio[j];
    int ci = le % CIP;
    int co = (le / CIP) % CO;
    int k = le / (CIP * CO);
    float v = (ci + CIO < CIRT) ? jb.src[j][((size_t)k * CIRT + CIO + ci) * CO + co] : 0.f;
    wt[e] = f2bf(v);
  }
}

__global__ __launch_bounds__(256) void k_pool(const unsigned char* __restrict__ mf,
                                              unsigned char* __restrict__ mc,
                                              int* __restrict__ list, int* __restrict__ cnt, int DC) {
  int v = blockIdx.x * 256 + threadIdx.x;
  int n = DC * DC * DC;
  if (v >= n) return;
  int w = v % DC, h = (v / DC) % DC, d = v / (DC * DC);
  int DF = 2 * DC;
  bool a = false;
  for (int i = 0; i < 2; i++)
    for (int j = 0; j < 2; j++)
      for (int k = 0; k < 2; k++)
        a |= (mf[(size_t)(((2 * d + i) * DF + (2 * h + j)) * DF + (2 * w + k))] != 0);
  mc[v] = a ? 1 : 0;
  if (a) { int pos = atomicAdd(cnt, 1); list[pos] = v; }
}

// ---------------------------------------------------------------------------
// Fused-BN MFMA conv. Persistent blocks: x = tile stride (32 voxels),
// y = co-block (CB). 8 waves = 2 voxel-groups x 4 tap-splits. Weight slice
// staged once in LDS, layout unit ((k*KCH+c)*4+kg)*(CB+1)+co -> each lane
// reads its own contiguous 16B (conflict-free). Input gathered raw f32 and
// normalized on gather (BN finalize from 8-replica f64 stats in prologue;
// inactive/OOB -> 0 via okf). Optional residual read or fused 1x1 shortcut
// dot in epilogue. Register-accumulated BN stats -> replicated f64 atomics.
// ---------------------------------------------------------------------------
template <int CIPAD, int CB, int KK, int DD, bool UP, bool NORM, int CIRAW, int SCCI>
__global__ __launch_bounds__(512) void k_conv10(
    const float* __restrict__ in, int istr, int icoff,
    const int* __restrict__ cntIn,
    const ushort_t* __restrict__ wt, int cot,
    const unsigned char* __restrict__ msk,
    const double* __restrict__ stA, const double* __restrict__ stB, int csplit,
    float* __restrict__ out, int ostr, int ooff,
    const float* __restrict__ res, int rstr,
    const float* __restrict__ scIn, const float* __restrict__ scW,
    double* __restrict__ stOut,
    const int* __restrict__ list, const int* __restrict__ cntOut) {
  constexpr int KCH = CIPAD / 32;
  constexpr int NCO = CB / 16;
  constexpr int TPS = (KK + 3) / 4;
  constexpr int CBP = CB + 1;
  constexpr int ETOT = 2 * NCO * 256;
  constexpr int NE = ETOT / 512;
  __shared__ ushort_t blds[KK * KCH * 4 * CBP * 8];
  __shared__ float red[4][2][NCO * 4][64];
  __shared__ float s_iv[CIPAD], s_mv[CIPAD];
  __shared__ float sred[2 * CB];
  __shared__ int vidx[32];

  const int n = cntOut[0];
  const int t = threadIdx.x, wv = t >> 6, ln = t & 63;
  const int vg = wv & 1, ks = wv >> 1;
  const int fr = ln & 15, kg = ln >> 4;
  const int coblk = blockIdx.y * CB;
  const int k0 = ks * TPS;

  // ---- stage weight slice into LDS (once) ----
  for (int e = t; e < KK * KCH * 4 * CB; e += 512) {
    int co = e % CB;
    int r2 = e / CB;
    int kgs = r2 & 3, r3 = r2 >> 2;
    int c = r3 % KCH, k = r3 / KCH;
    *(bf16x8*)(blds + ((size_t)r2 * CBP + co) * 8) =
        *(const bf16x8*)(wt + ((size_t)k * cot + coblk + co) * CIPAD + c * 32 + kgs * 8);
  }
  if (NORM && t < CIPAD) {
    int nIn = cntIn[0];
    const double* s = (t < csplit) ? (stA + t) : (stB + (t - csplit));
    double sm = 0.0, sq = 0.0;
#pragma unroll
    for (int r = 0; r < 8; r++) { sm += s[r * 256]; sq += s[r * 256 + 128]; }
    double mu = sm / nIn, var = sq / nIn - mu * mu;
    float iv = rsqrtf((float)fmax(var, 0.0) + 1e-4f);
    s_iv[t] = iv;
    s_mv[t] = (float)mu * iv;
  }
  if (t < 2 * CB) sred[t] = 0.f;
  __syncthreads();

  float ivv[KCH][8], mvv[KCH][8];
  if (NORM) {
#pragma unroll
    for (int c = 0; c < KCH; c++)
#pragma unroll
      for (int q = 0; q < 8; q++) {
        int ch = c * 32 + kg * 8 + q;
        ivv[c][q] = s_iv[ch];
        mvv[c][q] = s_mv[ch];
      }
  }

  float smr = 0.f, sqr = 0.f;
  constexpr int GDI = UP ? (DD / 2) : ((KK == 8) ? 2 * DD : DD);

  for (int tile = blockIdx.x; tile * 32 < n; tile += gridDim.x) {
    int base = tile * 32;
    if (t < 32) vidx[t] = (base + t < n) ? list[base + t] : -1;
    __syncthreads();

    int av = vidx[vg * 16 + fr];
    int vv = av < 0 ? 0 : av;
    int ad = vv / (DD * DD), ah = (vv / DD) % DD, aw = vv % DD;
    int pidx = 0, corner = -1;
    if (UP) {
      constexpr int DC = DD / 2;
      pidx = (((ad >> 1) * DC) + (ah >> 1)) * DC + (aw >> 1);
      corner = ((ad & 1) << 2) | ((ah & 1) << 1) | (aw & 1);
    }

    float aF[2][KCH][8];
    float okf[2];

    auto LOADT = [&](int st, int j) {
      int k = k0 + j;
      bool ok;
      int nix;
      if (UP) {
        ok = (av >= 0) && (corner == k);
        nix = ok ? pidx : 0;
      } else if (KK == 27) {
        int kc = (k < KK) ? k : KK - 1;
        int kd = kc / 9 - 1, kh = (kc / 3) % 3 - 1, kw = kc % 3 - 1;
        int nd = ad + kd, nh = ah + kh, nw = aw + kw;
        ok = (k < KK) && (av >= 0) && ((unsigned)nd < (unsigned)DD) &&
             ((unsigned)nh < (unsigned)DD) && ((unsigned)nw < (unsigned)DD);
        nix = ok ? (nd * DD + nh) * DD + nw : 0;
      } else {
        int kd = (k >> 2) & 1, kh = (k >> 1) & 1, kw = k & 1;
        ok = (av >= 0);
        nix = ok ? ((2 * ad + kd) * GDI + (2 * ah + kh)) * GDI + (2 * aw + kw) : 0;
      }
      if (NORM && msk) ok = ok && (msk[nix] != 0);
      okf[st] = ok ? 1.f : 0.f;
      if (CIRAW == 6) {
        if (kg == 0) {
          const float* ap = in + (size_t)nix * 6;
          aF[st][0][0] = ap[0]; aF[st][0][1] = ap[1]; aF[st][0][2] = ap[2];
          aF[st][0][3] = ap[3]; aF[st][0][4] = ap[4]; aF[st][0][5] = ap[5];
          aF[st][0][6] = 0.f;   aF[st][0][7] = 0.f;
        } else {
#pragma unroll
          for (int q = 0; q < 8; q++) aF[st][0][q] = 0.f;
        }
      } else {
#pragma unroll
        for (int c = 0; c < KCH; c++) {
          const float* ap = in + (size_t)nix * istr + icoff + c * 32 + kg * 8;
          float4 u0 = *(const float4*)ap;
          float4 u1 = *(const float4*)(ap + 4);
          aF[st][c][0] = u0.x; aF[st][c][1] = u0.y; aF[st][c][2] = u0.z; aF[st][c][3] = u0.w;
          aF[st][c][4] = u1.x; aF[st][c][5] = u1.y; aF[st][c][6] = u1.z; aF[st][c][7] = u1.w;
        }
      }
    };

    f32x4 acc[NCO];
#pragma unroll
    for (int f = 0; f < NCO; f++) acc[f] = (f32x4){0.f, 0.f, 0.f, 0.f};

    LOADT(0, 0);
#pragma unroll
    for (int j = 0; j < TPS; j++) {
      if (j + 1 < TPS) LOADT((j + 1) & 1, j + 1);
      if (k0 + j < KK) {
        const int st = j & 1;
#pragma unroll
        for (int c = 0; c < KCH; c++) {
          bf16x8 afr;
#pragma unroll
          for (int q = 0; q < 8; q++) {
            float xq = aF[st][c][q];
            float y;
            if (NORM) y = fmaxf(fmaf(xq, ivv[c][q], -mvv[c][q]), 0.f) * okf[st];
            else      y = xq * okf[st];
            afr[q] = (short)f2bf(y);
          }
#pragma unroll
          for (int f = 0; f < NCO; f++) {
            bf16x8 b = *(const bf16x8*)(blds +
                ((size_t)(((k0 + j) * KCH + c) * 4 + kg) * CBP + f * 16 + fr) * 8);
            acc[f] = __builtin_amdgcn_mfma_f32_16x16x32_bf16(afr, b, acc[f], 0, 0, 0);
          }
        }
      }
    }

#pragma unroll
    for (int f = 0; f < NCO; f++)
#pragma unroll
      for (int r = 0; r < 4; r++)
        red[ks][vg][f * 4 + r][ln] = acc[f][r];
    __syncthreads();

#pragma unroll
    for (int e0 = 0; e0 < NE; e0++) {
      int e = t + e0 * 512;
      int ln2 = e & 63, r = (e >> 6) & 3;
      int f = (e >> 8) % NCO;
      int vg2 = e / (256 * NCO);
      float sv = red[0][vg2][f * 4 + r][ln2] + red[1][vg2][f * 4 + r][ln2] +
                 red[2][vg2][f * 4 + r][ln2] + red[3][vg2][f * 4 + r][ln2];
      int slot = vg2 * 16 + (ln2 >> 4) * 4 + r;
      int ii = base + slot;
      int v = (ii < n) ? list[ii] : -1;
      if (v >= 0) {
        int gco = coblk + f * 16 + (ln2 & 15);
        float val = sv;
        if (SCCI > 0) {
          const float4* xr = (const float4*)(scIn + (size_t)v * SCCI);
          const float4* wq = (const float4*)(scW + (size_t)gco * SCCI);
          float a = 0.f;
#pragma unroll 8
          for (int c = 0; c < SCCI / 4; c++) {
            float4 xv = xr[c], wv_ = wq[c];
            a += xv.x * wv_.x + xv.y * wv_.y + xv.z * wv_.z + xv.w * wv_.w;
          }
          val += a;
        } else if (res) {
          val += res[(size_t)v * rstr + gco];
        }
        out[(size_t)v * ostr + ooff + gco] = val;
        smr += val;
        sqr += val * val;
      }
    }
    __syncthreads();
  }

  // ---- block stats -> LDS reduce -> replicated global f64 atomics ----
  {
    int myco = ((t >> 8) % NCO) * 16 + (t & 15);
    atomicAdd(&sred[myco], smr);
    atomicAdd(&sred[CB + myco], sqr);
  }
  __syncthreads();
  if (t < CB) {
    double* sr = stOut + (size_t)((int)blockIdx.x & 7) * 256;
    atomicAdd(&sr[coblk + t], (double)sred[t]);
    atomicAdd(&sr[128 + coblk + t], (double)sred[CB + t]);
  }
}

// final BN apply -> dense f32 d_out (zeros at inactive), replica finalize
__global__ __launch_bounds__(256) void k_bnout(const float* __restrict__ x,
                                               const unsigned char* __restrict__ m,
                                               const double* __restrict__ s,
                                               const int* __restrict__ cnt,
                                               float* __restrict__ out) {
  __shared__ float mu_s[32], inv_s[32];
  int t = threadIdx.x;
  int n = cnt[0];
  if (t < 32) {
    double sm = 0.0, sq = 0.0;
#pragma unroll
    for (int r = 0; r < 8; r++) { sm += s[r * 256 + t]; sq += s[r * 256 + 128 + t]; }
    double mu = sm / n;
    double var = sq / n - mu * mu;
    float iv = rsqrtf((float)fmax(var, 0.0) + 1e-4f);
    mu_s[t] = (float)mu * iv;
    inv_s[t] = iv;
  }
  __syncthreads();
  int gid = blockIdx.x * 256 + t;
  if (gid >= N1 * 8) return;
  int v = gid / 8;
  int c = (gid % 8) * 4;
  float4 o = make_float4(0.f, 0.f, 0.f, 0.f);
  if (m[v]) {
    float4 xv = *(const float4*)&x[(size_t)v * 32 + c];
    o.x = fmaxf(fmaf(xv.x, inv_s[c + 0], -mu_s[c + 0]), 0.f);
    o.y = fmaxf(fmaf(xv.y, inv_s[c + 1], -mu_s[c + 1]), 0.f);
    o.z = fmaxf(fmaf(xv.z, inv_s[c + 2], -mu_s[c + 2]), 0.f);
    o.w = fmaxf(fmaf(xv.w, inv_s[c + 3], -mu_s[c + 3]), 0.f);
  }
  *(float4*)&out[(size_t)v * 32 + c] = o;
}

// ---------------------------------------------------------------------------
// host launch
// ---------------------------------------------------------------------------
extern "C" void kernel_launch(void* const* d_in, const int* in_sizes, int n_in,
                              void* d_out, int out_size, void* d_ws, size_t ws_size,
                              hipStream_t stream) {
  float* W = (float*)d_ws;
  const float* x = (const float*)d_in[0];

  float* A    = W + OFF_A;
  float* R1   = W + OFF_R1;
  float* CAT1 = W + OFF_CAT1;
  float* T1R  = W + OFF_T1R;
  float* D1R  = W + OFF_D1R;
  float* R3   = W + OFF_R3;
  float* CAT2 = W + OFF_CAT2;
  float* T2R  = W + OFF_T2R;
  float* D2R  = W + OFF_D2R;
  float* R4   = W + OFF_R4;
  float* X3R  = W + OFF_X3R;
  ushort_t* WT = (ushort_t*)(W + OFF_WT);
  double* S0 = (double*)(W + OFF_STATS);
  int* CNT = (int*)(W + OFF_CNT);
  int* L1 = (int*)(W + OFF_L1);
  int* L2 = (int*)(W + OFF_L2);
  int* L3 = (int*)(W + OFF_L3);
  unsigned char* M1 = (unsigned char*)(W + OFF_M1);
  unsigned char* M2 = (unsigned char*)(W + OFF_M2);
  unsigned char* M3 = (unsigned char*)(W + OFF_M3);
  const float* wsc2 = (const float*)d_in[12];
  const float* wsc1 = (const float*)d_in[16];

  auto S = [&](int i) { return S0 + (size_t)i * 2048; };
  // slots: 0 x0, 1 b1a, 2 x1, 3 d1, 4 b2a, 5 x2, 6 d2, 7 b3a, 8 x3,
  //        9 u2, 10 h2, 11 t2, 12 u1, 13 h1, 14 t1, 15 dummy

  hipMemsetAsync(W + OFF_STATS, 0, (STATS_FLOATS + 16) * 4, stream);

  WJobs jb;
  const int srcIdx[16]  = {2, 3, 4, 5, 6, 7, 8, 9, 10, 13, 13, 14, 17, 18, 11, 15};
  const short cirtot[16]= {6, 32, 32, 32, 64, 64, 64, 96, 96, 128, 128, 64, 64, 32, 96, 64};
  const short cio[16]   = {0, 0, 0, 0, 0, 0, 0, 0, 0, 0, 64, 0, 0, 0, 0, 0};
  const short cipad[16] = {32, 32, 32, 32, 64, 64, 64, 96, 96, 64, 64, 64, 64, 32, 96, 64};
  const short couts[16] = {32, 32, 32, 64, 64, 64, 96, 96, 96, 64, 64, 64, 32, 32, 64, 32};
  for (int j = 0; j < 16; j++) {
    jb.src[j] = (const float*)d_in[srcIdx[j]];
    jb.cirtot[j] = cirtot[j]; jb.cio[j] = cio[j];
    jb.cipad[j] = cipad[j]; jb.cout[j] = couts[j];
    jb.start[j] = WTS[j];
  }
  jb.start[16] = WTS[16];

  k_prep<<<864, 256, 0, stream>>>(jb, x, M1, L1, CNT + 0, WT);
  k_pool<<<N2 / 256, 256, 0, stream>>>(M1, M2, L2, CNT + 1, DIM2);
  k_pool<<<(N3 + 255) / 256, 256, 0, stream>>>(M2, M3, L3, CNT + 2, DIM3);

  // ---- level 1 down ----
  k_conv10<32, 32, 27, D1, false, false, 6, 0><<<dim3(256, 1), 512, 0, stream>>>(
      x, 6, 0, CNT + 0, WT + WTS[0], 32, nullptr, S(0), S(0), 32,
      A, 32, 0, nullptr, 0, nullptr, nullptr, S(0), L1, CNT + 0);                 // x0
  k_conv10<32, 32, 27, D1, false, true, 0, 0><<<dim3(256, 1), 512, 0, stream>>>(
      A, 32, 0, CNT + 0, WT + WTS[1], 32, M1, S(0), S(0), 32,
      R1, 32, 0, nullptr, 0, nullptr, nullptr, S(1), L1, CNT + 0);                // b1a
  k_conv10<32, 32, 27, D1, false, true, 0, 0><<<dim3(256, 1), 512, 0, stream>>>(
      R1, 32, 0, CNT + 0, WT + WTS[2], 32, M1, S(1), S(1), 32,
      CAT1, 64, 0, A, 32, nullptr, nullptr, S(2), L1, CNT + 0);                   // x1
  k_conv10<32, 32, 8, DIM2, false, true, 0, 0><<<dim3(128, 2), 512, 0, stream>>>(
      CAT1, 64, 0, CNT + 0, WT + WTS[3], 64, M1, S(2), S(2), 32,
      D1R, 64, 0, nullptr, 0, nullptr, nullptr, S(3), L2, CNT + 1);               // d1

  // ---- level 2 ----
  k_conv10<64, 16, 27, DIM2, false, true, 0, 0><<<dim3(64, 4), 512, 0, stream>>>(
      D1R, 64, 0, CNT + 1, WT + WTS[4], 64, M2, S(3), S(3), 64,
      R3, 64, 0, nullptr, 0, nullptr, nullptr, S(4), L2, CNT + 1);                // b2a
  k_conv10<64, 16, 27, DIM2, false, true, 0, 0><<<dim3(64, 4), 512, 0, stream>>>(
      R3, 64, 0, CNT + 1, WT + WTS[5], 64, M2, S(4), S(4), 64,
      CAT2, 128, 0, D1R, 64, nullptr, nullptr, S(5), L2, CNT + 1);                // x2
  k_conv10<64, 32, 8, DIM3, false, true, 0, 0><<<dim3(54, 3), 512, 0, stream>>>(
      CAT2, 128, 0, CNT + 1, WT + WTS[6], 96, M2, S(5), S(5), 64,
      D2R, 96, 0, nullptr, 0, nullptr, nullptr, S(6), L3, CNT + 2);               // d2

  // ---- level 3 ----
  k_conv10<96, 16, 27, DIM3, false, true, 0, 0><<<dim3(54, 6), 512, 0, stream>>>(
      D2R, 96, 0, CNT + 2, WT + WTS[7], 96, M3, S(6), S(6), 96,
      R4, 96, 0, nullptr, 0, nullptr, nullptr, S(7), L3, CNT + 2);                // b3a
  k_conv10<96, 16, 27, DIM3, false, true, 0, 0><<<dim3(54, 6), 512, 0, stream>>>(
      R4, 96, 0, CNT + 2, WT + WTS[8], 96, M3, S(7), S(7), 96,
      X3R, 96, 0, D2R, 96, nullptr, nullptr, S(8), L3, CNT + 2);                  // x3
  k_conv10<96, 32, 8, DIM2, true, true, 0, 0><<<dim3(128, 2), 512, 0, stream>>>(
      X3R, 96, 0, CNT + 2, WT + WTS[14], 64, nullptr, S(8), S(8), 96,
      CAT2, 128, 64, nullptr, 0, nullptr, nullptr, S(9), L2, CNT + 1);            // u2

  // ---- tail level 2 (h2 as two 64-ci halves) ----
  k_conv10<64, 16, 27, DIM2, false, true, 0, 0><<<dim3(64, 4), 512, 0, stream>>>(
      CAT2, 128, 0, CNT + 1, WT + WTS[9], 64, M2, S(5), S(5), 64,
      R3, 64, 0, nullptr, 0, nullptr, nullptr, S(15), L2, CNT + 1);               // h2A
  k_conv10<64, 16, 27, DIM2, false, true, 0, 0><<<dim3(64, 4), 512, 0, stream>>>(
      CAT2, 128, 64, CNT + 1, WT + WTS[10], 64, M2, S(9), S(9), 64,
      R3, 64, 0, R3, 64, nullptr, nullptr, S(10), L2, CNT + 1);                   // h2B (+res)
  k_conv10<64, 16, 27, DIM2, false, true, 0, 128><<<dim3(64, 4), 512, 0, stream>>>(
      R3, 64, 0, CNT + 1, WT + WTS[11], 64, M2, S(10), S(10), 64,
      T2R, 64, 0, nullptr, 0, CAT2, wsc2, S(11), L2, CNT + 1);                    // t2 (+sc)
  k_conv10<64, 32, 8, D1, true, true, 0, 0><<<dim3(256, 1), 512, 0, stream>>>(
      T2R, 64, 0, CNT + 1, WT + WTS[15], 32, nullptr, S(11), S(11), 64,
      CAT1, 64, 32, nullptr, 0, nullptr, nullptr, S(12), L1, CNT + 0);            // u1

  // ---- tail level 1 ----
  k_conv10<64, 16, 27, D1, false, true, 0, 0><<<dim3(128, 2), 512, 0, stream>>>(
      CAT1, 64, 0, CNT + 0, WT + WTS[12], 32, M1, S(2), S(12), 32,
      R1, 32, 0, nullptr, 0, nullptr, nullptr, S(13), L1, CNT + 0);               // h1
  k_conv10<32, 32, 27, D1, false, true, 0, 64><<<dim3(256, 1), 512, 0, stream>>>(
      R1, 32, 0, CNT + 0, WT + WTS[13], 32, M1, S(13), S(13), 32,
      T1R, 32, 0, nullptr, 0, CAT1, wsc1, S(14), L1, CNT + 0);                    // t1 (+sc)

  k_bnout<<<N1 * 8 / 256, 256, 0, stream>>>(T1R, M1, S(14), CNT + 0, (float*)d_out);
}